// Round 5
// baseline (344.247 us; speedup 1.0000x reference)
//
#include <hip/hip_runtime.h>
#include <hip/hip_bf16.h>
#include <stdint.h>

// Problem constants
constexpr int CB  = 4;     // batch
constexpr int CS  = 2048;  // seq len
constexpr int CH  = 1024;  // hidden
constexpr int CNH = 16;    // heads
constexpr int CDH = 64;    // head dim
constexpr int CM  = CB * CS;  // 8192 rows

typedef __bf16 bf16x8 __attribute__((ext_vector_type(8)));
typedef float  f32x4  __attribute__((ext_vector_type(4)));

// round-to-nearest-even f32 -> bf16 (bit pattern)
__device__ __forceinline__ unsigned short f2bf(float f) {
    union { float f; unsigned u; } c; c.f = f;
    unsigned u = c.u;
    unsigned r = (u + 0x7fffu + ((u >> 16) & 1u)) >> 16;
    return (unsigned short)r;
}

// async global->LDS, 16B per lane. LDS dest = base + lane*16 (wave-uniform base).
__device__ __forceinline__ void gl_lds16(const void* g, void* l) {
    __builtin_amdgcn_global_load_lds((const __attribute__((address_space(1))) uint32_t*)g,
                                     (__attribute__((address_space(3))) uint32_t*)l,
                                     16, 0, 0);
}

__device__ __forceinline__ float fexp2(float x) {
#if __has_builtin(__builtin_amdgcn_exp2f)
    return __builtin_amdgcn_exp2f(x);
#else
    return exp2f(x);
#endif
}

// pack two f32 -> one dword of 2 bf16 (RNE). No builtin on gfx950 (m240) -> asm.
__device__ __forceinline__ unsigned cvtpk_bf16(float lo, float hi) {
    unsigned r;
    asm("v_cvt_pk_bf16_f32 %0, %1, %2" : "=v"(r) : "v"(lo), "v"(hi));
    return r;
}

// a' = [a_r0, a_r1, b_r0, b_r1]; b' = [a_r2, a_r3, b_r2, b_r3]  (16-lane rows)
__device__ __forceinline__ void pl32swap(unsigned &a, unsigned &b) {
#if __has_builtin(__builtin_amdgcn_permlane32_swap)
    auto r = __builtin_amdgcn_permlane32_swap(a, b, false, false);
    a = r[0]; b = r[1];
#else
    int lane = threadIdx.x & 63;
    unsigned as = (unsigned)__shfl((int)a, lane ^ 32);
    unsigned bs = (unsigned)__shfl((int)b, lane ^ 32);
    unsigned na = (lane < 32) ? a : bs;
    unsigned nb = (lane < 32) ? as : b;
    a = na; b = nb;
#endif
}

// a' = [a_r0, b_r0, a_r2, b_r2]; b' = [a_r1, b_r1, a_r3, b_r3]
__device__ __forceinline__ void pl16swap(unsigned &a, unsigned &b) {
#if __has_builtin(__builtin_amdgcn_permlane16_swap)
    auto r = __builtin_amdgcn_permlane16_swap(a, b, false, false);
    a = r[0]; b = r[1];
#else
    unsigned as = __builtin_amdgcn_ds_swizzle(a, 0x401F);  // lane ^ 16 within 32-halves
    unsigned bs = __builtin_amdgcn_ds_swizzle(b, 0x401F);
    int odd = (threadIdx.x >> 4) & 1;
    unsigned na = odd ? bs : a;
    unsigned nb = odd ? b : as;
    a = na; b = nb;
#endif
}

// 1/sqrt(dh) * log2(e): folded into Q at projection time
constexpr float C_SC = 0.125f * 1.44269504f;

// ---------------- fp32 -> bf16 convert (X + 3 weights, one launch) ----------------
__global__ __launch_bounds__(256) void cvt_all(const float* __restrict__ hs,
                                               const float* __restrict__ w0,
                                               const float* __restrict__ w1,
                                               const float* __restrict__ w2,
                                               unsigned short* __restrict__ Xb,
                                               unsigned short* __restrict__ Wb) {
    int z = blockIdx.y;
    const float* src; unsigned short* dst; int n4;
    if (z == 0)      { src = hs; dst = Xb;              n4 = CM * CH / 4; }
    else if (z == 1) { src = w0; dst = Wb;              n4 = CH * CH / 4; }
    else if (z == 2) { src = w1; dst = Wb + CH * CH;    n4 = CH * CH / 4; }
    else             { src = w2; dst = Wb + 2 * CH * CH; n4 = CH * CH / 4; }
    int i = blockIdx.x * blockDim.x + threadIdx.x;
    if (i < n4) {
        float4 v = ((const float4*)src)[i];
        ushort4 o;
        o.x = f2bf(v.x); o.y = f2bf(v.y); o.z = f2bf(v.z); o.w = f2bf(v.w);
        ((ushort4*)dst)[i] = o;
    }
}

// ---------------- fused QKV projection GEMM (pipelined + LDS-repacked epilogue) ----
// C[m,n] = sum_k X[m,k] * W[n,k] + bias[n]
// z=0 (Q): out [b,h,s,d], pre-scaled by C_SC. z=1 (K): [b,h,s,d]. z=2 (V): [b,h,d,s].
__global__ __launch_bounds__(256) void qkv_gemm(
    const unsigned short* __restrict__ Xb,
    const unsigned short* __restrict__ Wb,
    const float* __restrict__ bq, const float* __restrict__ bk, const float* __restrict__ bv,
    unsigned short* __restrict__ Qo,
    unsigned short* __restrict__ Ko,
    unsigned short* __restrict__ Vt)
{
    // staging (32 KB, double-buffered) and epilogue tile (34 KB) alias the same LDS
    __shared__ alignas(16) unsigned char smem[34816];
    typedef unsigned short (*tile_t)[128][32];
    tile_t As = (tile_t)smem;                 // [2][128][32]
    tile_t Bs = (tile_t)(smem + 16384);       // [2][128][32]
    typedef unsigned short (*ep_t)[136];      // [128][136] (pad -> 16B-aligned rows)
    ep_t Ep = (ep_t)smem;

    const int tid  = threadIdx.x;
    const int wave = tid >> 6, lane = tid & 63;
    const int wm = wave >> 1, wn = wave & 1;
    const int col = lane & 15, quad = lane >> 4;
    const int gm = blockIdx.x * 128, gn = blockIdx.y * 128;
    const int z  = blockIdx.z;
    const unsigned short* W = Wb + (size_t)z * CH * CH;

    f32x4 zero = {0.f, 0.f, 0.f, 0.f};
    f32x4 acc[4][4];
    for (int i = 0; i < 4; i++) for (int j = 0; j < 4; j++) acc[i][j] = zero;

    const int arow = lane >> 2;
    const int acol = (lane & 3) * 8;

    auto stage = [&](int buf, int k0) {
        for (int c = 0; c < 2; ++c) {
            int r0 = wave * 32 + c * 16;
            gl_lds16(Xb + (size_t)(gm + r0 + arow) * CH + k0 + acol, &As[buf][r0][0]);
            gl_lds16(W  + (size_t)(gn + r0 + arow) * CH + k0 + acol, &Bs[buf][r0][0]);
        }
    };

    stage(0, 0);
    for (int kk = 0; kk < 32; ++kk) {
        int cur = kk & 1;
        __syncthreads();
        if (kk < 31) stage(cur ^ 1, (kk + 1) * 32);
        bf16x8 af[4], bfm[4];
        for (int i = 0; i < 4; i++)
            af[i] = *(const bf16x8*)&As[cur][wm * 64 + i * 16 + col][quad * 8];
        for (int j = 0; j < 4; j++)
            bfm[j] = *(const bf16x8*)&Bs[cur][wn * 64 + j * 16 + col][quad * 8];
        for (int i = 0; i < 4; i++)
            for (int j = 0; j < 4; j++)
                acc[i][j] = __builtin_amdgcn_mfma_f32_16x16x32_bf16(af[i], bfm[j], acc[i][j], 0, 0, 0);
    }

    __syncthreads();   // staging buffers dead; reuse LDS for epilogue tile

    const float* bias = (z == 0) ? bq : (z == 1) ? bk : bv;
    const int bb = gm >> 11, ss0 = gm & 2047;
    const int h0 = gn >> 6;          // block's n-range spans 2 heads

    if (z == 2) {
        // transpose tile into Ep[n_local][m_local]; m-contiguous r-values pack as b32
        for (int j = 0; j < 4; j++) {
            int nl = wn * 64 + j * 16 + col;
            float bias_v = bias[gn + nl];
            for (int i = 0; i < 4; i++) {
                int ml = wm * 64 + i * 16 + quad * 4;
                unsigned d0 = (unsigned)f2bf(acc[i][j][0] + bias_v) |
                              ((unsigned)f2bf(acc[i][j][1] + bias_v) << 16);
                unsigned d1 = (unsigned)f2bf(acc[i][j][2] + bias_v) |
                              ((unsigned)f2bf(acc[i][j][3] + bias_v) << 16);
                *(unsigned*)&Ep[nl][ml]     = d0;
                *(unsigned*)&Ep[nl][ml + 2] = d1;
            }
        }
        __syncthreads();
        for (int p = 0; p < 8; p++) {
            int nl = p * 16 + (tid >> 4);
            int seg = tid & 15;
            uint4 v = *(const uint4*)&Ep[nl][seg * 8];
            int h = h0 + (nl >> 6), d = nl & 63;
            *(uint4*)(Vt + ((size_t)(bb * CNH + h) * CDH + d) * CS + ss0 + seg * 8) = v;
        }
    } else {
        const float mulf = (z == 0) ? C_SC : 1.0f;
        for (int j = 0; j < 4; j++) {
            int nl = wn * 64 + j * 16 + col;
            float bias_v = bias[gn + nl];
            for (int i = 0; i < 4; i++)
                for (int r = 0; r < 4; r++) {
                    int ml = wm * 64 + i * 16 + quad * 4 + r;
                    Ep[ml][nl] = f2bf((acc[i][j][r] + bias_v) * mulf);
                }
        }
        __syncthreads();
        unsigned short* dst01 = (z == 0) ? Qo : Ko;
        for (int p = 0; p < 8; p++) {
            int ml = p * 16 + (tid >> 4);
            int half2 = (tid >> 3) & 1, seg = tid & 7;
            uint4 v = *(const uint4*)&Ep[ml][half2 * 64 + seg * 8];
            int h = h0 + half2;
            *(uint4*)(dst01 + ((size_t)(bb * CNH + h) * CS + ss0 + ml) * CDH + seg * 8) = v;
        }
    }
}

// ---------------- flash attention v10: barrier-free, per-wave register K/V ---------
// grid: 512 blocks (8 q-blocks x 64 bh) x 256 threads = 4 waves x 64 q rows.
// K/V is L2-resident (XCD head-pinning: XCD c owns heads [8c,8c+8), 4 MB = its L2;
// R4 measured FETCH 24.7 MB). So NO LDS staging: each wave loads its K/V MFMA
// fragments directly global->register (16B/lane, 64B-segment coalesced, ~200cy L2),
// software-prefetched one phase ahead (K(t+1) at body start, V(t+1) after PV(t),
// K-ks1 between QK half-batches). ZERO in-loop barriers -> the 2 waves/SIMD drift
// anti-phase and one wave's MFMA bursts overlap the other's exp2/pack VALU chain
// (R4 showed lockstep capped both pipes at ~40%).
// Swapped QK^T + in-register P redistribute (cvt_pk + permlane), static softmax
// (log2-domain, Q pre-scaled), setprio on MFMA clusters.
__global__ __launch_bounds__(256, 2) void flash_attn(
    const unsigned short* __restrict__ Q,    // [B*h, S, d] (pre-scaled)
    const unsigned short* __restrict__ K,    // [B*h, S, d]
    const unsigned short* __restrict__ Vt,   // [B*h, d, S]
    const int* __restrict__ mask,            // [B, S]
    float* __restrict__ out)                 // [B, S, H]
{
    __shared__ unsigned int Mbits[64];       // 2048-bit mask (only LDS use)

    const int tid  = threadIdx.x;
    const int wave = tid >> 6, lane = tid & 63;
    const int col = lane & 15, quad = lane >> 4;

    // XCD-aware bijective remap (512 wgs, 8 XCDs, launch order x-fastest)
    const int wg   = blockIdx.y * gridDim.x + blockIdx.x;
    const int nid  = (wg & 7) * 64 + (wg >> 3);
    const int bh   = nid >> 3;            // head index: XCD c gets heads [8c, 8c+8)
    const int qblk = nid & 7;
    const int bI = bh >> 4, hI = bh & 15;
    const int q0 = qblk * 256 + wave * 64;

    const unsigned short* Qp = Q + (size_t)bh * CS * CDH;
    const char* Kp8 = (const char*)(K  + (size_t)bh * CS * CDH);
    const char* Vp8 = (const char*)(Vt + (size_t)bh * CDH * CS);

    // mask -> bitmask in LDS; single barrier of the kernel
    {
        const int* mg = mask + bI * CS;
        for (int j = 0; j < 8; j++) {
            int idx = wave * 512 + j * 64 + lane;
            unsigned long long bal = __ballot(mg[idx] != 0);
            if (lane == 0) {
                Mbits[wave * 16 + j * 2]     = (unsigned int)bal;
                Mbits[wave * 16 + j * 2 + 1] = (unsigned int)(bal >> 32);
            }
        }
    }
    __syncthreads();

    // Q fragments in registers: frag[n=col][k=quad*8+j], 64 q rows per wave
    bf16x8 aq[4][2];
    #pragma unroll
    for (int i = 0; i < 4; i++)
        #pragma unroll
        for (int ks = 0; ks < 2; ks++)
            aq[i][ks] = *(const bf16x8*)(Qp + (size_t)(q0 + i * 16 + col) * CDH + ks * 32 + quad * 8);

    bf16x8 onesb;
    {
        union { unsigned short u; __bf16 b; } ob; ob.u = 0x3F80;  // bf16 1.0
        #pragma unroll
        for (int j = 0; j < 8; j++) onesb[j] = ob.b;
    }

    f32x4 zero = {0.f, 0.f, 0.f, 0.f};
    f32x4 o[4][4], lfr[4];
    #pragma unroll
    for (int i = 0; i < 4; i++) {
        lfr[i] = zero;
        #pragma unroll
        for (int id = 0; id < 4; id++) o[i][id] = zero;
    }

    // per-lane 32-bit byte offsets (SGPR base + VGPR offset form)
    // K frag (ik,ks): byte = kt*8192 + ik*2048 + col*128 + ks*64 + quad*16
    // V frag (ks,id): byte = (id*16+col)*4096 + kt*128 + ks*64 + quad*16
    unsigned voKa = (unsigned)(col * 128 + quad * 16);   // ik 0,1 via imm {0,2048}
    unsigned voKb = voKa + 4096u;                        // ik 2,3
    unsigned voV0 = (unsigned)(col * 4096 + quad * 16);  // id=0
    unsigned voV1 = voV0 + 16u * 4096u;
    unsigned voV2 = voV0 + 32u * 4096u;
    unsigned voV3 = voV0 + 48u * 4096u;

    bf16x8 kf[4];      // one ks half-batch of K fragments (time-shared ks0/ks1)
    bf16x8 vf[2][4];   // full V tile fragments
    f32x4  sfr[4][4];

    auto ldK = [&](unsigned ks) {
        kf[0] = *(const bf16x8*)(Kp8 + (voKa + ks * 64u));
        kf[1] = *(const bf16x8*)(Kp8 + (voKa + 2048u + ks * 64u));
        kf[2] = *(const bf16x8*)(Kp8 + (voKb + ks * 64u));
        kf[3] = *(const bf16x8*)(Kp8 + (voKb + 2048u + ks * 64u));
    };
    auto ldV = [&]() {
        #pragma unroll
        for (int ks = 0; ks < 2; ks++) {
            vf[ks][0] = *(const bf16x8*)(Vp8 + (voV0 + (unsigned)ks * 64u));
            vf[ks][1] = *(const bf16x8*)(Vp8 + (voV1 + (unsigned)ks * 64u));
            vf[ks][2] = *(const bf16x8*)(Vp8 + (voV2 + (unsigned)ks * 64u));
            vf[ks][3] = *(const bf16x8*)(Vp8 + (voV3 + (unsigned)ks * 64u));
        }
    };

    // prologue: QK(0).  V(0) issued first so it lands during QK+softmax.
    ldV();
    ldK(0);
    #pragma unroll
    for (int i = 0; i < 4; i++)
        #pragma unroll
        for (int ik = 0; ik < 4; ik++) sfr[i][ik] = zero;
    __builtin_amdgcn_s_setprio(1);
    #pragma unroll
    for (int i = 0; i < 4; i++)
        #pragma unroll
        for (int ik = 0; ik < 4; ik++)
            sfr[i][ik] = __builtin_amdgcn_mfma_f32_16x16x32_bf16(kf[ik], aq[i][0], sfr[i][ik], 0, 0, 0);
    __builtin_amdgcn_s_setprio(0);
    ldK(1);
    __builtin_amdgcn_s_setprio(1);
    #pragma unroll
    for (int i = 0; i < 4; i++)
        #pragma unroll
        for (int ik = 0; ik < 4; ik++)
            sfr[i][ik] = __builtin_amdgcn_mfma_f32_16x16x32_bf16(kf[ik], aq[i][1], sfr[i][ik], 0, 0, 0);
    __builtin_amdgcn_s_setprio(0);
    voKa += 8192u; voKb += 8192u;

    for (int kt = 0; kt < 32; ++kt) {
        // prefetch K(kt+1) ks0 early: lands under softmax(kt)+PV(kt)
        if (kt < 31) ldK(0);

        // mask add only if some kv masked (uniform branch; all-ones in practice)
        unsigned int w0 = Mbits[kt * 2], w1 = Mbits[kt * 2 + 1];
        if ((w0 & w1) != 0xFFFFFFFFu) {
            #pragma unroll
            for (int ik = 0; ik < 4; ik++)
                #pragma unroll
                for (int r = 0; r < 4; r++) {
                    int kv = ik * 16 + quad * 4 + r;
                    unsigned bit = (kv < 32) ? (w0 >> kv) : (w1 >> (kv - 32));
                    float madd = (bit & 1u) ? 0.f : -1.0e30f;
                    #pragma unroll
                    for (int i = 0; i < 4; i++) sfr[i][ik][r] += madd;
                }
        }

        // softmax(kt) + PV(kt), interleaved per i (PV(i-1) MFMA overlaps softmax(i))
        #pragma unroll
        for (int i = 0; i < 4; i++) {
            unsigned c[4][2];
            #pragma unroll
            for (int ik = 0; ik < 4; ik++)
                #pragma unroll
                for (int h = 0; h < 2; h++)
                    c[ik][h] = cvtpk_bf16(fexp2(sfr[i][ik][2 * h]), fexp2(sfr[i][ik][2 * h + 1]));

            unsigned a0 = c[0][0], b0 = c[1][0]; pl32swap(a0, b0); pl16swap(a0, b0); // ap0.dw0, ap0.dw2
            unsigned a1 = c[0][1], b1 = c[1][1]; pl32swap(a1, b1); pl16swap(a1, b1); // ap0.dw1, ap0.dw3
            unsigned a2 = c[2][0], b2 = c[3][0]; pl32swap(a2, b2); pl16swap(a2, b2); // ap1.dw0, ap1.dw2
            unsigned a3 = c[2][1], b3 = c[3][1]; pl32swap(a3, b3); pl16swap(a3, b3); // ap1.dw1, ap1.dw3

            uint4 lo4; lo4.x = a0; lo4.y = a1; lo4.z = b0; lo4.w = b1;
            uint4 hi4; hi4.x = a2; hi4.y = a3; hi4.z = b2; hi4.w = b3;
            bf16x8 ap0, ap1;
            __builtin_memcpy(&ap0, &lo4, 16);
            __builtin_memcpy(&ap1, &hi4, 16);

            __builtin_amdgcn_s_setprio(1);
            #pragma unroll
            for (int id = 0; id < 4; id++)
                o[i][id] = __builtin_amdgcn_mfma_f32_16x16x32_bf16(ap0, vf[0][id], o[i][id], 0, 0, 0);
            lfr[i] = __builtin_amdgcn_mfma_f32_16x16x32_bf16(ap0, onesb, lfr[i], 0, 0, 0);
            #pragma unroll
            for (int id = 0; id < 4; id++)
                o[i][id] = __builtin_amdgcn_mfma_f32_16x16x32_bf16(ap1, vf[1][id], o[i][id], 0, 0, 0);
            lfr[i] = __builtin_amdgcn_mfma_f32_16x16x32_bf16(ap1, onesb, lfr[i], 0, 0, 0);
            __builtin_amdgcn_s_setprio(0);
        }

        if (kt < 31) {
            // V(kt+1): vf free now; lands under QK(kt+1) + softmax(kt+1)
            voV0 += 128u; voV1 += 128u; voV2 += 128u; voV3 += 128u;
            ldV();

            // QK(kt+1): kf(ks0) prefetched at body start; ks1 issued between halves
            #pragma unroll
            for (int i = 0; i < 4; i++)
                #pragma unroll
                for (int ik = 0; ik < 4; ik++) sfr[i][ik] = zero;
            __builtin_amdgcn_s_setprio(1);
            #pragma unroll
            for (int i = 0; i < 4; i++)
                #pragma unroll
                for (int ik = 0; ik < 4; ik++)
                    sfr[i][ik] = __builtin_amdgcn_mfma_f32_16x16x32_bf16(kf[ik], aq[i][0], sfr[i][ik], 0, 0, 0);
            __builtin_amdgcn_s_setprio(0);
            ldK(1);
            __builtin_amdgcn_s_setprio(1);
            #pragma unroll
            for (int i = 0; i < 4; i++)
                #pragma unroll
                for (int ik = 0; ik < 4; ik++)
                    sfr[i][ik] = __builtin_amdgcn_mfma_f32_16x16x32_bf16(kf[ik], aq[i][1], sfr[i][ik], 0, 0, 0);
            __builtin_amdgcn_s_setprio(0);
            voKa += 8192u; voKb += 8192u;
        }
    }

    // epilogue: out[b][s][h*64+d] = O / l
    #pragma unroll
    for (int i = 0; i < 4; i++)
        #pragma unroll
        for (int r = 0; r < 4; r++) {
            int sI = q0 + i * 16 + quad * 4 + r;
            float inv = 1.0f / lfr[i][r];
            #pragma unroll
            for (int id = 0; id < 4; id++)
                out[((size_t)(bI * CS + sI)) * CH + hI * CDH + id * 16 + col] = o[i][id][r] * inv;
        }
}

extern "C" void kernel_launch(void* const* d_in, const int* in_sizes, int n_in,
                              void* d_out, int out_size, void* d_ws, size_t ws_size,
                              hipStream_t stream) {
    const float* hs  = (const float*)d_in[0];
    const int*  mask = (const int*)d_in[1];
    const float* Wq  = (const float*)d_in[2];
    const float* bq  = (const float*)d_in[3];
    const float* Wk  = (const float*)d_in[4];
    const float* bk  = (const float*)d_in[5];
    const float* Wv  = (const float*)d_in[6];
    const float* bv  = (const float*)d_in[7];
    float* out = (float*)d_out;

    char* ws = (char*)d_ws;
    unsigned short* Xb = (unsigned short*)(ws);                    // 16 MB
    unsigned short* Wb = (unsigned short*)(ws + 16777216);         // 6 MB
    unsigned short* Qb = (unsigned short*)(ws + 23068672);         // 16 MB
    unsigned short* Kb = (unsigned short*)(ws + 39845888);         // 16 MB
    unsigned short* Vt = (unsigned short*)(ws + 56623104);         // 16 MB

    cvt_all<<<dim3(8192, 4), 256, 0, stream>>>(hs, Wq, Wk, Wv, Xb, Wb);

    qkv_gemm<<<dim3(CM / 128, CH / 128, 3), 256, 0, stream>>>(Xb, Wb, bq, bk, bv, Qb, Kb, Vt);

    flash_attn<<<dim3(8, 64), 256, 0, stream>>>(Qb, Kb, Vt, mask, out);
}

// Round 8
// 245.539 us; speedup vs baseline: 1.4020x; 1.4020x over previous
//
#include <hip/hip_runtime.h>
#include <hip/hip_bf16.h>
#include <stdint.h>

// Problem constants
constexpr int CB  = 4;     // batch
constexpr int CS  = 2048;  // seq len
constexpr int CH  = 1024;  // hidden
constexpr int CNH = 16;    // heads
constexpr int CDH = 64;    // head dim
constexpr int CM  = CB * CS;  // 8192 rows

typedef __bf16 bf16x8 __attribute__((ext_vector_type(8)));
typedef float  f32x4  __attribute__((ext_vector_type(4)));

// round-to-nearest-even f32 -> bf16 (bit pattern)
__device__ __forceinline__ unsigned short f2bf(float f) {
    union { float f; unsigned u; } c; c.f = f;
    unsigned u = c.u;
    unsigned r = (u + 0x7fffu + ((u >> 16) & 1u)) >> 16;
    return (unsigned short)r;
}

// async global->LDS, 16B per lane. LDS dest = base + lane*16 (wave-uniform base).
__device__ __forceinline__ void gl_lds16(const void* g, void* l) {
    __builtin_amdgcn_global_load_lds((const __attribute__((address_space(1))) uint32_t*)g,
                                     (__attribute__((address_space(3))) uint32_t*)l,
                                     16, 0, 0);
}

__device__ __forceinline__ float fexp2(float x) {
#if __has_builtin(__builtin_amdgcn_exp2f)
    return __builtin_amdgcn_exp2f(x);
#else
    return exp2f(x);
#endif
}

// pack two f32 -> one dword of 2 bf16 (RNE). No builtin on gfx950 (m240) -> asm.
__device__ __forceinline__ unsigned cvtpk_bf16(float lo, float hi) {
    unsigned r;
    asm("v_cvt_pk_bf16_f32 %0, %1, %2" : "=v"(r) : "v"(lo), "v"(hi));
    return r;
}

// a' = [a_r0, a_r1, b_r0, b_r1]; b' = [a_r2, a_r3, b_r2, b_r3]  (16-lane rows)
__device__ __forceinline__ void pl32swap(unsigned &a, unsigned &b) {
#if __has_builtin(__builtin_amdgcn_permlane32_swap)
    auto r = __builtin_amdgcn_permlane32_swap(a, b, false, false);
    a = r[0]; b = r[1];
#else
    int lane = threadIdx.x & 63;
    unsigned as = (unsigned)__shfl((int)a, lane ^ 32);
    unsigned bs = (unsigned)__shfl((int)b, lane ^ 32);
    unsigned na = (lane < 32) ? a : bs;
    unsigned nb = (lane < 32) ? as : b;
    a = na; b = nb;
#endif
}

// a' = [a_r0, b_r0, a_r2, b_r2]; b' = [a_r1, b_r1, a_r3, b_r3]
__device__ __forceinline__ void pl16swap(unsigned &a, unsigned &b) {
#if __has_builtin(__builtin_amdgcn_permlane16_swap)
    auto r = __builtin_amdgcn_permlane16_swap(a, b, false, false);
    a = r[0]; b = r[1];
#else
    unsigned as = __builtin_amdgcn_ds_swizzle(a, 0x401F);  // lane ^ 16 within 32-halves
    unsigned bs = __builtin_amdgcn_ds_swizzle(b, 0x401F);
    int odd = (threadIdx.x >> 4) & 1;
    unsigned na = odd ? bs : a;
    unsigned nb = odd ? b : as;
    a = na; b = nb;
#endif
}

// 1/sqrt(dh) * log2(e): folded into Q at projection time
constexpr float C_SC = 0.125f * 1.44269504f;

// ---------------- fp32 -> bf16 convert (X + 3 weights, one launch) ----------------
// exact-sized 1-D grid: 8192 blocks for X, 1024 per weight (no dead blocks).
// BISECT PROBE: if this round fails with absmax 2.203 again, THIS re-grid is the
// deterministic bug from R6/R7 (flash is reverted to the R4-exact passing binary).
__global__ __launch_bounds__(256) void cvt_all(const float* __restrict__ hs,
                                               const float* __restrict__ w0,
                                               const float* __restrict__ w1,
                                               const float* __restrict__ w2,
                                               unsigned short* __restrict__ Xb,
                                               unsigned short* __restrict__ Wb) {
    int b = blockIdx.x;
    const float* src; unsigned short* dst; int i;
    if (b < 8192) {
        src = hs; dst = Xb;
        i = b * 256 + (int)threadIdx.x;            // < CM*CH/4 exactly
    } else {
        int t = b - 8192;
        int z = t >> 10;                           // 0,1,2
        src = (z == 0) ? w0 : (z == 1) ? w1 : w2;
        dst = Wb + z * CH * CH;
        i = (t & 1023) * 256 + (int)threadIdx.x;   // < CH*CH/4 exactly
    }
    float4 v = ((const float4*)src)[i];
    ushort4 o;
    o.x = f2bf(v.x); o.y = f2bf(v.y); o.z = f2bf(v.z); o.w = f2bf(v.w);
    ((ushort4*)dst)[i] = o;
}

// ---------------- fused QKV projection GEMM (pipelined + LDS-repacked epilogue) ----
// C[m,n] = sum_k X[m,k] * W[n,k] + bias[n]
// z=0 (Q): out [b,h,s,d], pre-scaled by C_SC. z=1 (K): [b,h,s,d]. z=2 (V): [b,h,d,s].
__global__ __launch_bounds__(256) void qkv_gemm(
    const unsigned short* __restrict__ Xb,
    const unsigned short* __restrict__ Wb,
    const float* __restrict__ bq, const float* __restrict__ bk, const float* __restrict__ bv,
    unsigned short* __restrict__ Qo,
    unsigned short* __restrict__ Ko,
    unsigned short* __restrict__ Vt)
{
    // staging (32 KB, double-buffered) and epilogue tile (34 KB) alias the same LDS
    __shared__ alignas(16) unsigned char smem[34816];
    typedef unsigned short (*tile_t)[128][32];
    tile_t As = (tile_t)smem;                 // [2][128][32]
    tile_t Bs = (tile_t)(smem + 16384);       // [2][128][32]
    typedef unsigned short (*ep_t)[136];      // [128][136] (pad -> 16B-aligned rows)
    ep_t Ep = (ep_t)smem;

    const int tid  = threadIdx.x;
    const int wave = tid >> 6, lane = tid & 63;
    const int wm = wave >> 1, wn = wave & 1;
    const int col = lane & 15, quad = lane >> 4;
    const int gm = blockIdx.x * 128, gn = blockIdx.y * 128;
    const int z  = blockIdx.z;
    const unsigned short* W = Wb + (size_t)z * CH * CH;

    f32x4 zero = {0.f, 0.f, 0.f, 0.f};
    f32x4 acc[4][4];
    for (int i = 0; i < 4; i++) for (int j = 0; j < 4; j++) acc[i][j] = zero;

    const int arow = lane >> 2;
    const int acol = (lane & 3) * 8;

    auto stage = [&](int buf, int k0) {
        for (int c = 0; c < 2; ++c) {
            int r0 = wave * 32 + c * 16;
            gl_lds16(Xb + (size_t)(gm + r0 + arow) * CH + k0 + acol, &As[buf][r0][0]);
            gl_lds16(W  + (size_t)(gn + r0 + arow) * CH + k0 + acol, &Bs[buf][r0][0]);
        }
    };

    stage(0, 0);
    for (int kk = 0; kk < 32; ++kk) {
        int cur = kk & 1;
        __syncthreads();
        if (kk < 31) stage(cur ^ 1, (kk + 1) * 32);
        bf16x8 af[4], bfm[4];
        for (int i = 0; i < 4; i++)
            af[i] = *(const bf16x8*)&As[cur][wm * 64 + i * 16 + col][quad * 8];
        for (int j = 0; j < 4; j++)
            bfm[j] = *(const bf16x8*)&Bs[cur][wn * 64 + j * 16 + col][quad * 8];
        for (int i = 0; i < 4; i++)
            for (int j = 0; j < 4; j++)
                acc[i][j] = __builtin_amdgcn_mfma_f32_16x16x32_bf16(af[i], bfm[j], acc[i][j], 0, 0, 0);
    }

    __syncthreads();   // staging buffers dead; reuse LDS for epilogue tile

    const float* bias = (z == 0) ? bq : (z == 1) ? bk : bv;
    const int bb = gm >> 11, ss0 = gm & 2047;
    const int h0 = gn >> 6;          // block's n-range spans 2 heads

    if (z == 2) {
        // transpose tile into Ep[n_local][m_local]; m-contiguous r-values pack as b32
        for (int j = 0; j < 4; j++) {
            int nl = wn * 64 + j * 16 + col;
            float bias_v = bias[gn + nl];
            for (int i = 0; i < 4; i++) {
                int ml = wm * 64 + i * 16 + quad * 4;
                unsigned d0 = (unsigned)f2bf(acc[i][j][0] + bias_v) |
                              ((unsigned)f2bf(acc[i][j][1] + bias_v) << 16);
                unsigned d1 = (unsigned)f2bf(acc[i][j][2] + bias_v) |
                              ((unsigned)f2bf(acc[i][j][3] + bias_v) << 16);
                *(unsigned*)&Ep[nl][ml]     = d0;
                *(unsigned*)&Ep[nl][ml + 2] = d1;
            }
        }
        __syncthreads();
        for (int p = 0; p < 8; p++) {
            int nl = p * 16 + (tid >> 4);
            int seg = tid & 15;
            uint4 v = *(const uint4*)&Ep[nl][seg * 8];
            int h = h0 + (nl >> 6), d = nl & 63;
            *(uint4*)(Vt + ((size_t)(bb * CNH + h) * CDH + d) * CS + ss0 + seg * 8) = v;
        }
    } else {
        const float mulf = (z == 0) ? C_SC : 1.0f;
        for (int j = 0; j < 4; j++) {
            int nl = wn * 64 + j * 16 + col;
            float bias_v = bias[gn + nl];
            for (int i = 0; i < 4; i++)
                for (int r = 0; r < 4; r++) {
                    int ml = wm * 64 + i * 16 + quad * 4 + r;
                    Ep[ml][nl] = f2bf((acc[i][j][r] + bias_v) * mulf);
                }
        }
        __syncthreads();
        unsigned short* dst01 = (z == 0) ? Qo : Ko;
        for (int p = 0; p < 8; p++) {
            int ml = p * 16 + (tid >> 4);
            int half2 = (tid >> 3) & 1, seg = tid & 7;
            uint4 v = *(const uint4*)&Ep[ml][half2 * 64 + seg * 8];
            int h = h0 + half2;
            *(uint4*)(dst01 + ((size_t)(bb * CNH + h) * CS + ss0 + ml) * CDH + seg * 8) = v;
        }
    }
}

// ---------------- flash attention v9 (R4-exact revert): triple-buffer + vmcnt ------
// grid: 512 blocks (8 q-blocks x 64 bh) x 256 threads = 4 waves x 64 q rows.
// This is the verbatim R4 kernel (250.8 µs total, flash 88 µs, PASSING).
// setprio fences retained: R6/R7 showed removing them breaks correctness
// deterministically (mechanism unresolved); they are load-bearing for the schedule.
// Triple-buffered K/V staging, counted s_waitcnt vmcnt(4), one raw s_barrier/iter,
// XCD head-pinning (XCD c owns heads [8c,8c+8), 4 MB = its L2; FETCH 24.7 MB),
// swapped QK^T, in-register P redistribute, static log2-domain softmax.
__global__ __launch_bounds__(256, 2) void flash_attn(
    const unsigned short* __restrict__ Q,    // [B*h, S, d] (pre-scaled)
    const unsigned short* __restrict__ K,    // [B*h, S, d]
    const unsigned short* __restrict__ Vt,   // [B*h, d, S]
    const int* __restrict__ mask,            // [B, S]
    float* __restrict__ out)                 // [B, S, H]
{
    __shared__ alignas(16) unsigned short Ks[3][64][64];   // 24 KB, triple-buffered
    __shared__ alignas(16) unsigned short Vs[3][64][64];   // 24 KB, [d][kv]
    __shared__ unsigned int Mbits[64];                     // 2048-bit mask

    const int tid  = threadIdx.x;
    const int wave = tid >> 6, lane = tid & 63;
    const int col = lane & 15, quad = lane >> 4;

    // XCD-aware bijective remap (512 wgs, 8 XCDs, launch order x-fastest)
    const int wg   = blockIdx.y * gridDim.x + blockIdx.x;
    const int nid  = (wg & 7) * 64 + (wg >> 3);
    const int bh   = nid >> 3;            // head index: XCD c gets heads [8c, 8c+8)
    const int qblk = nid & 7;
    const int bI = bh >> 4, hI = bh & 15;
    const int q0 = qblk * 256 + wave * 64;

    const unsigned short* Qp = Q  + (size_t)bh * CS * CDH;
    const unsigned short* Kp = K  + (size_t)bh * CS * CDH;
    const unsigned short* Vp = Vt + (size_t)bh * CDH * CS;

    // mask -> bitmask in LDS (drained below; first loop barrier publishes it)
    {
        const int* mg = mask + bI * CS;
        for (int j = 0; j < 8; j++) {
            int idx = wave * 512 + j * 64 + lane;
            unsigned long long bal = __ballot(mg[idx] != 0);
            if (lane == 0) {
                Mbits[wave * 16 + j * 2]     = (unsigned int)bal;
                Mbits[wave * 16 + j * 2 + 1] = (unsigned int)(bal >> 32);
            }
        }
    }

    // Q fragments in registers: frag[n=col][k=quad*8+j], 64 q rows per wave
    bf16x8 aq[4][2];
    for (int i = 0; i < 4; i++)
        for (int ks = 0; ks < 2; ks++)
            aq[i][ks] = *(const bf16x8*)(Qp + (size_t)(q0 + i * 16 + col) * CDH + ks * 32 + quad * 8);

    bf16x8 onesb;
    {
        union { unsigned short u; __bf16 b; } ob; ob.u = 0x3F80;  // bf16 1.0
        for (int j = 0; j < 8; j++) onesb[j] = ob.b;
    }

    f32x4 zero = {0.f, 0.f, 0.f, 0.f};
    f32x4 o[4][4], lfr[4];
    for (int i = 0; i < 4; i++) {
        lfr[i] = zero;
        for (int id = 0; id < 4; id++) o[i][id] = zero;
    }

    const int srow = lane >> 3;
    const int schk = (lane & 7) ^ srow;      // swizzled global chunk index

    // one stage call = 4 gl_lds per wave (2 c-steps x {K,V}); waves cover 64 rows
    auto stageKV = [&](int buf, int t) {
        const unsigned short* kg = Kp + (size_t)t * 64 * CDH;
        for (int c = 0; c < 2; c++) {
            int r0 = wave * 16 + c * 8;
            gl_lds16(kg + (size_t)(r0 + srow) * CDH + schk * 8, &Ks[buf][r0][0]);
            gl_lds16(Vp + (size_t)(r0 + srow) * CS + t * 64 + schk * 8, &Vs[buf][r0][0]);
        }
    };

    // prologue: 2 tiles in flight; drain LDS queue so Mbits publish at first barrier
    stageKV(0, 0);
    stageKV(1, 1);
    asm volatile("s_waitcnt lgkmcnt(0)" ::: "memory");

    int cur = 0, sp = 2;
    for (int kt = 0; kt < 32; ++kt) {
        // batch kt done (4 newest = batch kt+1 stay in flight); last iter drains all
        if (kt < 31) asm volatile("s_waitcnt vmcnt(4)" ::: "memory");
        else         asm volatile("s_waitcnt vmcnt(0)" ::: "memory");
        asm volatile("s_barrier" ::: "memory");
        if (kt < 30) stageKV(sp, kt + 2);   // overwrites buffer last read at kt-1

        // S'^T = (K Q^T) (log2-domain): sfr[i][ik][r] = S'[q=i*16+col][kv=ik*16+quad*4+r]
        f32x4 sfr[4][4];
        for (int i = 0; i < 4; i++) for (int ik = 0; ik < 4; ik++) sfr[i][ik] = zero;
        for (int ks = 0; ks < 2; ks++) {
            bf16x8 bkf[4];
            for (int ik = 0; ik < 4; ik++)
                bkf[ik] = *(const bf16x8*)&Ks[cur][ik * 16 + col][((ks * 4 + quad) ^ (col & 7)) * 8];
            __builtin_amdgcn_s_setprio(1);
            for (int i = 0; i < 4; i++)
                for (int ik = 0; ik < 4; ik++)
                    sfr[i][ik] = __builtin_amdgcn_mfma_f32_16x16x32_bf16(bkf[ik], aq[i][ks], sfr[i][ik], 0, 0, 0);
            __builtin_amdgcn_s_setprio(0);
        }

        // mask add only if some kv masked (uniform branch; all-ones in practice)
        unsigned int w0 = Mbits[kt * 2], w1 = Mbits[kt * 2 + 1];
        if ((w0 & w1) != 0xFFFFFFFFu) {
            for (int ik = 0; ik < 4; ik++)
                for (int r = 0; r < 4; r++) {
                    int kv = ik * 16 + quad * 4 + r;
                    unsigned bit = (kv < 32) ? (w0 >> kv) : (w1 >> (kv - 32));
                    float madd = (bit & 1u) ? 0.f : -1.0e30f;
                    for (int i = 0; i < 4; i++) sfr[i][ik][r] += madd;
                }
        }

        // V fragments hoisted (i-invariant): frag[n=col -> d][k=quad*8+j -> kv]
        bf16x8 bvf[2][4];
        for (int ks = 0; ks < 2; ks++)
            for (int id = 0; id < 4; id++)
                bvf[ks][id] = *(const bf16x8*)&Vs[cur][id * 16 + col][((ks * 4 + quad) ^ (col & 7)) * 8];

        // P = 2^(s'); pack to bf16 pairs, redistribute in-register into PV A-frags.
        for (int i = 0; i < 4; i++) {
            unsigned c[4][2];
            for (int ik = 0; ik < 4; ik++)
                for (int h = 0; h < 2; h++)
                    c[ik][h] = cvtpk_bf16(fexp2(sfr[i][ik][2 * h]), fexp2(sfr[i][ik][2 * h + 1]));

            unsigned a0 = c[0][0], b0 = c[1][0]; pl32swap(a0, b0); pl16swap(a0, b0); // ap0.dw0, ap0.dw2
            unsigned a1 = c[0][1], b1 = c[1][1]; pl32swap(a1, b1); pl16swap(a1, b1); // ap0.dw1, ap0.dw3
            unsigned a2 = c[2][0], b2 = c[3][0]; pl32swap(a2, b2); pl16swap(a2, b2); // ap1.dw0, ap1.dw2
            unsigned a3 = c[2][1], b3 = c[3][1]; pl32swap(a3, b3); pl16swap(a3, b3); // ap1.dw1, ap1.dw3

            uint4 lo4; lo4.x = a0; lo4.y = a1; lo4.z = b0; lo4.w = b1;
            uint4 hi4; hi4.x = a2; hi4.y = a3; hi4.z = b2; hi4.w = b3;
            bf16x8 ap0, ap1;
            __builtin_memcpy(&ap0, &lo4, 16);
            __builtin_memcpy(&ap1, &hi4, 16);

            __builtin_amdgcn_s_setprio(1);
            for (int id = 0; id < 4; id++)
                o[i][id] = __builtin_amdgcn_mfma_f32_16x16x32_bf16(ap0, bvf[0][id], o[i][id], 0, 0, 0);
            lfr[i] = __builtin_amdgcn_mfma_f32_16x16x32_bf16(ap0, onesb, lfr[i], 0, 0, 0);
            for (int id = 0; id < 4; id++)
                o[i][id] = __builtin_amdgcn_mfma_f32_16x16x32_bf16(ap1, bvf[1][id], o[i][id], 0, 0, 0);
            lfr[i] = __builtin_amdgcn_mfma_f32_16x16x32_bf16(ap1, onesb, lfr[i], 0, 0, 0);
            __builtin_amdgcn_s_setprio(0);
        }

        cur = (cur + 1 == 3) ? 0 : cur + 1;
        sp  = (sp  + 1 == 3) ? 0 : sp  + 1;
    }

    // epilogue: out[b][s][h*64+d] = O / l
    for (int i = 0; i < 4; i++)
        for (int r = 0; r < 4; r++) {
            int sI = q0 + i * 16 + quad * 4 + r;
            float inv = 1.0f / lfr[i][r];
            for (int id = 0; id < 4; id++)
                out[((size_t)(bI * CS + sI)) * CH + hI * CDH + id * 16 + col] = o[i][id][r] * inv;
        }
}

extern "C" void kernel_launch(void* const* d_in, const int* in_sizes, int n_in,
                              void* d_out, int out_size, void* d_ws, size_t ws_size,
                              hipStream_t stream) {
    const float* hs  = (const float*)d_in[0];
    const int*  mask = (const int*)d_in[1];
    const float* Wq  = (const float*)d_in[2];
    const float* bq  = (const float*)d_in[3];
    const float* Wk  = (const float*)d_in[4];
    const float* bk  = (const float*)d_in[5];
    const float* Wv  = (const float*)d_in[6];
    const float* bv  = (const float*)d_in[7];
    float* out = (float*)d_out;

    char* ws = (char*)d_ws;
    unsigned short* Xb = (unsigned short*)(ws);                    // 16 MB
    unsigned short* Wb = (unsigned short*)(ws + 16777216);         // 6 MB
    unsigned short* Qb = (unsigned short*)(ws + 23068672);         // 16 MB
    unsigned short* Kb = (unsigned short*)(ws + 39845888);         // 16 MB
    unsigned short* Vt = (unsigned short*)(ws + 56623104);         // 16 MB

    cvt_all<<<dim3(11264), 256, 0, stream>>>(hs, Wq, Wk, Wv, Xb, Wb);

    qkv_gemm<<<dim3(CM / 128, CH / 128, 3), 256, 0, stream>>>(Xb, Wb, bq, bk, bv, Qb, Kb, Vt);

    flash_attn<<<dim3(8, 64), 256, 0, stream>>>(Qb, Kb, Vt, mask, out);
}

// Round 9
// 236.578 us; speedup vs baseline: 1.4551x; 1.0379x over previous
//
#include <hip/hip_runtime.h>
#include <hip/hip_cooperative_groups.h>
#include <hip/hip_bf16.h>
#include <stdint.h>

namespace cg = cooperative_groups;

// Problem constants
constexpr int CB  = 4;     // batch
constexpr int CS  = 2048;  // seq len
constexpr int CH  = 1024;  // hidden
constexpr int CNH = 16;    // heads
constexpr int CDH = 64;    // head dim
constexpr int CM  = CB * CS;  // 8192 rows

typedef __bf16 bf16x8 __attribute__((ext_vector_type(8)));
typedef float  f32x4  __attribute__((ext_vector_type(4)));

// round-to-nearest-even f32 -> bf16 (bit pattern)
__device__ __forceinline__ unsigned short f2bf(float f) {
    union { float f; unsigned u; } c; c.f = f;
    unsigned u = c.u;
    unsigned r = (u + 0x7fffu + ((u >> 16) & 1u)) >> 16;
    return (unsigned short)r;
}

// async global->LDS, 16B per lane. LDS dest = base + lane*16 (wave-uniform base).
__device__ __forceinline__ void gl_lds16(const void* g, void* l) {
    __builtin_amdgcn_global_load_lds((const __attribute__((address_space(1))) uint32_t*)g,
                                     (__attribute__((address_space(3))) uint32_t*)l,
                                     16, 0, 0);
}

__device__ __forceinline__ float fexp2(float x) {
#if __has_builtin(__builtin_amdgcn_exp2f)
    return __builtin_amdgcn_exp2f(x);
#else
    return exp2f(x);
#endif
}

// pack two f32 -> one dword of 2 bf16 (RNE). No builtin on gfx950 (m240) -> asm.
__device__ __forceinline__ unsigned cvtpk_bf16(float lo, float hi) {
    unsigned r;
    asm("v_cvt_pk_bf16_f32 %0, %1, %2" : "=v"(r) : "v"(lo), "v"(hi));
    return r;
}

// a' = [a_r0, a_r1, b_r0, b_r1]; b' = [a_r2, a_r3, b_r2, b_r3]  (16-lane rows)
__device__ __forceinline__ void pl32swap(unsigned &a, unsigned &b) {
#if __has_builtin(__builtin_amdgcn_permlane32_swap)
    auto r = __builtin_amdgcn_permlane32_swap(a, b, false, false);
    a = r[0]; b = r[1];
#else
    int lane = threadIdx.x & 63;
    unsigned as = (unsigned)__shfl((int)a, lane ^ 32);
    unsigned bs = (unsigned)__shfl((int)b, lane ^ 32);
    unsigned na = (lane < 32) ? a : bs;
    unsigned nb = (lane < 32) ? as : b;
    a = na; b = nb;
#endif
}

// a' = [a_r0, b_r0, a_r2, b_r2]; b' = [a_r1, b_r1, a_r3, b_r3]
__device__ __forceinline__ void pl16swap(unsigned &a, unsigned &b) {
#if __has_builtin(__builtin_amdgcn_permlane16_swap)
    auto r = __builtin_amdgcn_permlane16_swap(a, b, false, false);
    a = r[0]; b = r[1];
#else
    unsigned as = __builtin_amdgcn_ds_swizzle(a, 0x401F);  // lane ^ 16 within 32-halves
    unsigned bs = __builtin_amdgcn_ds_swizzle(b, 0x401F);
    int odd = (threadIdx.x >> 4) & 1;
    unsigned na = odd ? bs : a;
    unsigned nb = odd ? b : as;
    a = na; b = nb;
#endif
}

// 1/sqrt(dh) * log2(e): folded into Q at projection time
constexpr float C_SC = 0.125f * 1.44269504f;

// ================= phase 1: fp32 -> bf16 convert (grid-stride body) ================
__device__ __forceinline__ void cvt_body(const float* __restrict__ hs,
                                         const float* __restrict__ w0,
                                         const float* __restrict__ w1,
                                         const float* __restrict__ w2,
                                         unsigned short* __restrict__ Xb,
                                         unsigned short* __restrict__ Wb) {
    for (int b = blockIdx.x; b < 11264; b += gridDim.x) {
        const float* src; unsigned short* dst; int i;
        if (b < 8192) {
            src = hs; dst = Xb;
            i = b * 256 + (int)threadIdx.x;            // < CM*CH/4 exactly
        } else {
            int t = b - 8192;
            int z = t >> 10;                           // 0,1,2
            src = (z == 0) ? w0 : (z == 1) ? w1 : w2;
            dst = Wb + z * CH * CH;
            i = (t & 1023) * 256 + (int)threadIdx.x;   // < CH*CH/4 exactly
        }
        float4 v = ((const float4*)src)[i];
        ushort4 o;
        o.x = f2bf(v.x); o.y = f2bf(v.y); o.z = f2bf(v.z); o.w = f2bf(v.w);
        ((ushort4*)dst)[i] = o;
    }
}

// ================= phase 2: one 128x128 QKV-GEMM tile (t in [0,1536)) ==============
// t decode: x = t%64 -> gm, y = (t/64)%8 -> gn, z = t/512 (0:Q 1:K 2:V)
__device__ __forceinline__ void qkv_tile(int t, unsigned char* smem,
    const unsigned short* __restrict__ Xb,
    const unsigned short* __restrict__ Wb,
    const float* __restrict__ bq, const float* __restrict__ bk, const float* __restrict__ bv,
    unsigned short* __restrict__ Qo,
    unsigned short* __restrict__ Ko,
    unsigned short* __restrict__ Vt)
{
    __syncthreads();   // inter-tile safety: prior tile's LDS reads done before restage

    typedef unsigned short (*tile_t)[128][32];
    tile_t As = (tile_t)smem;                 // [2][128][32]
    tile_t Bs = (tile_t)(smem + 16384);       // [2][128][32]
    typedef unsigned short (*ep_t)[136];      // [128][136] (pad -> 16B-aligned rows)
    ep_t Ep = (ep_t)smem;

    const int tid  = threadIdx.x;
    const int wave = tid >> 6, lane = tid & 63;
    const int wm = wave >> 1, wn = wave & 1;
    const int col = lane & 15, quad = lane >> 4;
    const int gm = (t & 63) * 128, gn = ((t >> 6) & 7) * 128;
    const int z  = t >> 9;
    const unsigned short* W = Wb + (size_t)z * CH * CH;

    f32x4 zero = {0.f, 0.f, 0.f, 0.f};
    f32x4 acc[4][4];
    for (int i = 0; i < 4; i++) for (int j = 0; j < 4; j++) acc[i][j] = zero;

    const int arow = lane >> 2;
    const int acol = (lane & 3) * 8;

    auto stage = [&](int buf, int k0) {
        for (int c = 0; c < 2; ++c) {
            int r0 = wave * 32 + c * 16;
            gl_lds16(Xb + (size_t)(gm + r0 + arow) * CH + k0 + acol, &As[buf][r0][0]);
            gl_lds16(W  + (size_t)(gn + r0 + arow) * CH + k0 + acol, &Bs[buf][r0][0]);
        }
    };

    stage(0, 0);
    for (int kk = 0; kk < 32; ++kk) {
        int cur = kk & 1;
        __syncthreads();
        if (kk < 31) stage(cur ^ 1, (kk + 1) * 32);
        bf16x8 af[4], bfm[4];
        for (int i = 0; i < 4; i++)
            af[i] = *(const bf16x8*)&As[cur][wm * 64 + i * 16 + col][quad * 8];
        for (int j = 0; j < 4; j++)
            bfm[j] = *(const bf16x8*)&Bs[cur][wn * 64 + j * 16 + col][quad * 8];
        for (int i = 0; i < 4; i++)
            for (int j = 0; j < 4; j++)
                acc[i][j] = __builtin_amdgcn_mfma_f32_16x16x32_bf16(af[i], bfm[j], acc[i][j], 0, 0, 0);
    }

    __syncthreads();   // staging buffers dead; reuse LDS for epilogue tile

    const float* bias = (z == 0) ? bq : (z == 1) ? bk : bv;
    const int bb = gm >> 11, ss0 = gm & 2047;
    const int h0 = gn >> 6;          // block's n-range spans 2 heads

    if (z == 2) {
        // transpose tile into Ep[n_local][m_local]; m-contiguous r-values pack as b32
        for (int j = 0; j < 4; j++) {
            int nl = wn * 64 + j * 16 + col;
            float bias_v = bias[gn + nl];
            for (int i = 0; i < 4; i++) {
                int ml = wm * 64 + i * 16 + quad * 4;
                unsigned d0 = (unsigned)f2bf(acc[i][j][0] + bias_v) |
                              ((unsigned)f2bf(acc[i][j][1] + bias_v) << 16);
                unsigned d1 = (unsigned)f2bf(acc[i][j][2] + bias_v) |
                              ((unsigned)f2bf(acc[i][j][3] + bias_v) << 16);
                *(unsigned*)&Ep[nl][ml]     = d0;
                *(unsigned*)&Ep[nl][ml + 2] = d1;
            }
        }
        __syncthreads();
        for (int p = 0; p < 8; p++) {
            int nl = p * 16 + (tid >> 4);
            int seg = tid & 15;
            uint4 v = *(const uint4*)&Ep[nl][seg * 8];
            int h = h0 + (nl >> 6), d = nl & 63;
            *(uint4*)(Vt + ((size_t)(bb * CNH + h) * CDH + d) * CS + ss0 + seg * 8) = v;
        }
    } else {
        const float mulf = (z == 0) ? C_SC : 1.0f;
        for (int j = 0; j < 4; j++) {
            int nl = wn * 64 + j * 16 + col;
            float bias_v = bias[gn + nl];
            for (int i = 0; i < 4; i++)
                for (int r = 0; r < 4; r++) {
                    int ml = wm * 64 + i * 16 + quad * 4 + r;
                    Ep[ml][nl] = f2bf((acc[i][j][r] + bias_v) * mulf);
                }
        }
        __syncthreads();
        unsigned short* dst01 = (z == 0) ? Qo : Ko;
        for (int p = 0; p < 8; p++) {
            int ml = p * 16 + (tid >> 4);
            int half2 = (tid >> 3) & 1, seg = tid & 7;
            uint4 v = *(const uint4*)&Ep[ml][half2 * 64 + seg * 8];
            int h = h0 + half2;
            *(uint4*)(dst01 + ((size_t)(bb * CNH + h) * CS + ss0 + ml) * CDH + seg * 8) = v;
        }
    }
}

// ================= phase 3: flash attention (R1-proven dbuf body + XCD remap) ======
// wg in [0,512). 4 waves x 64 q rows. Double-buffered K/V via global_load_lds,
// __syncthreads per iter (proven schedule), setprio pinning (load-bearing, R6/R7),
// XCD head-pinning, swapped QK^T, in-register P redistribute, static log2 softmax.
__device__ __forceinline__ void flash_body(unsigned char* smem, int wg,
    const unsigned short* __restrict__ Q,    // [B*h, S, d] (pre-scaled)
    const unsigned short* __restrict__ K,    // [B*h, S, d]
    const unsigned short* __restrict__ Vt,   // [B*h, d, S]
    const int* __restrict__ mask,            // [B, S]
    float* __restrict__ out)                 // [B, S, H]
{
    typedef unsigned short (*kv2_t)[64][64];
    kv2_t Ks = (kv2_t)smem;                          // [2][64][64], 16 KB
    kv2_t Vs = (kv2_t)(smem + 16384);                // [2][64][64] ([d][kv])
    unsigned int* Mbits = (unsigned int*)(smem + 32768);  // 2048-bit mask

    const int tid  = threadIdx.x;
    const int wave = tid >> 6, lane = tid & 63;
    const int col = lane & 15, quad = lane >> 4;

    // XCD-aware bijective remap (512 wgs, 8 XCDs)
    const int nid  = (wg & 7) * 64 + (wg >> 3);
    const int bh   = nid >> 3;            // head index: XCD c gets heads [8c, 8c+8)
    const int qblk = nid & 7;
    const int bI = bh >> 4, hI = bh & 15;
    const int q0 = qblk * 256 + wave * 64;

    const unsigned short* Qp = Q  + (size_t)bh * CS * CDH;
    const unsigned short* Kp = K  + (size_t)bh * CS * CDH;
    const unsigned short* Vp = Vt + (size_t)bh * CDH * CS;

    // mask -> bitmask in LDS (first loop barrier publishes it)
    {
        const int* mg = mask + bI * CS;
        for (int j = 0; j < 8; j++) {
            int idx = wave * 512 + j * 64 + lane;
            unsigned long long bal = __ballot(mg[idx] != 0);
            if (lane == 0) {
                Mbits[wave * 16 + j * 2]     = (unsigned int)bal;
                Mbits[wave * 16 + j * 2 + 1] = (unsigned int)(bal >> 32);
            }
        }
    }

    // Q fragments in registers: frag[n=col][k=quad*8+j], 64 q rows per wave
    bf16x8 aq[4][2];
    for (int i = 0; i < 4; i++)
        for (int ks = 0; ks < 2; ks++)
            aq[i][ks] = *(const bf16x8*)(Qp + (size_t)(q0 + i * 16 + col) * CDH + ks * 32 + quad * 8);

    bf16x8 onesb;
    {
        union { unsigned short u; __bf16 b; } ob; ob.u = 0x3F80;  // bf16 1.0
        for (int j = 0; j < 8; j++) onesb[j] = ob.b;
    }

    f32x4 zero = {0.f, 0.f, 0.f, 0.f};
    f32x4 o[4][4], lfr[4];
    for (int i = 0; i < 4; i++) {
        lfr[i] = zero;
        for (int id = 0; id < 4; id++) o[i][id] = zero;
    }

    const int srow = lane >> 3;
    const int schk = (lane & 7) ^ srow;      // swizzled global chunk index

    auto stageKV = [&](int buf, int t) {
        const unsigned short* kg = Kp + (size_t)t * 64 * CDH;
        for (int c = 0; c < 2; c++) {
            int r0 = wave * 16 + c * 8;
            gl_lds16(kg + (size_t)(r0 + srow) * CDH + schk * 8, &Ks[buf][r0][0]);
            gl_lds16(Vp + (size_t)(r0 + srow) * CS + t * 64 + schk * 8, &Vs[buf][r0][0]);
        }
    };

    stageKV(0, 0);
    for (int kt = 0; kt < 32; ++kt) {
        int cur = kt & 1;
        __syncthreads();
        if (kt < 31) stageKV(cur ^ 1, kt + 1);

        // S'^T = (K Q^T) (log2-domain): sfr[i][ik][r] = S'[q=i*16+col][kv=ik*16+quad*4+r]
        f32x4 sfr[4][4];
        for (int i = 0; i < 4; i++) for (int ik = 0; ik < 4; ik++) sfr[i][ik] = zero;
        for (int ks = 0; ks < 2; ks++) {
            bf16x8 bkf[4];
            for (int ik = 0; ik < 4; ik++)
                bkf[ik] = *(const bf16x8*)&Ks[cur][ik * 16 + col][((ks * 4 + quad) ^ (col & 7)) * 8];
            __builtin_amdgcn_s_setprio(1);
            for (int i = 0; i < 4; i++)
                for (int ik = 0; ik < 4; ik++)
                    sfr[i][ik] = __builtin_amdgcn_mfma_f32_16x16x32_bf16(bkf[ik], aq[i][ks], sfr[i][ik], 0, 0, 0);
            __builtin_amdgcn_s_setprio(0);
        }

        // mask add only if some kv masked (uniform branch; all-ones in practice)
        unsigned int w0 = Mbits[kt * 2], w1 = Mbits[kt * 2 + 1];
        if ((w0 & w1) != 0xFFFFFFFFu) {
            for (int ik = 0; ik < 4; ik++)
                for (int r = 0; r < 4; r++) {
                    int kv = ik * 16 + quad * 4 + r;
                    unsigned bit = (kv < 32) ? (w0 >> kv) : (w1 >> (kv - 32));
                    float madd = (bit & 1u) ? 0.f : -1.0e30f;
                    for (int i = 0; i < 4; i++) sfr[i][ik][r] += madd;
                }
        }

        // V fragments hoisted (i-invariant): frag[n=col -> d][k=quad*8+j -> kv]
        bf16x8 bvf[2][4];
        for (int ks = 0; ks < 2; ks++)
            for (int id = 0; id < 4; id++)
                bvf[ks][id] = *(const bf16x8*)&Vs[cur][id * 16 + col][((ks * 4 + quad) ^ (col & 7)) * 8];

        // P = 2^(s'); pack to bf16 pairs, redistribute in-register into PV A-frags.
        for (int i = 0; i < 4; i++) {
            unsigned c[4][2];
            for (int ik = 0; ik < 4; ik++)
                for (int h = 0; h < 2; h++)
                    c[ik][h] = cvtpk_bf16(fexp2(sfr[i][ik][2 * h]), fexp2(sfr[i][ik][2 * h + 1]));

            unsigned a0 = c[0][0], b0 = c[1][0]; pl32swap(a0, b0); pl16swap(a0, b0); // ap0.dw0, ap0.dw2
            unsigned a1 = c[0][1], b1 = c[1][1]; pl32swap(a1, b1); pl16swap(a1, b1); // ap0.dw1, ap0.dw3
            unsigned a2 = c[2][0], b2 = c[3][0]; pl32swap(a2, b2); pl16swap(a2, b2); // ap1.dw0, ap1.dw2
            unsigned a3 = c[2][1], b3 = c[3][1]; pl32swap(a3, b3); pl16swap(a3, b3); // ap1.dw1, ap1.dw3

            uint4 lo4; lo4.x = a0; lo4.y = a1; lo4.z = b0; lo4.w = b1;
            uint4 hi4; hi4.x = a2; hi4.y = a3; hi4.z = b2; hi4.w = b3;
            bf16x8 ap0, ap1;
            __builtin_memcpy(&ap0, &lo4, 16);
            __builtin_memcpy(&ap1, &hi4, 16);

            __builtin_amdgcn_s_setprio(1);
            for (int id = 0; id < 4; id++)
                o[i][id] = __builtin_amdgcn_mfma_f32_16x16x32_bf16(ap0, bvf[0][id], o[i][id], 0, 0, 0);
            lfr[i] = __builtin_amdgcn_mfma_f32_16x16x32_bf16(ap0, onesb, lfr[i], 0, 0, 0);
            for (int id = 0; id < 4; id++)
                o[i][id] = __builtin_amdgcn_mfma_f32_16x16x32_bf16(ap1, bvf[1][id], o[i][id], 0, 0, 0);
            lfr[i] = __builtin_amdgcn_mfma_f32_16x16x32_bf16(ap1, onesb, lfr[i], 0, 0, 0);
            __builtin_amdgcn_s_setprio(0);
        }
    }

    // epilogue: out[b][s][h*64+d] = O / l
    for (int i = 0; i < 4; i++)
        for (int r = 0; r < 4; r++) {
            int sI = q0 + i * 16 + quad * 4 + r;
            float inv = 1.0f / lfr[i][r];
            for (int id = 0; id < 4; id++)
                out[((size_t)(bI * CS + sI)) * CH + hI * CDH + id * 16 + col] = o[i][id][r] * inv;
        }
}

// ================= fused cooperative kernel ========================================
// 1024 blocks x 256 threads, 4 blocks/CU (VGPR<=128 via launch_bounds, LDS 34816).
// phase1 cvt (11 iters/block, exact) | grid.sync | phase2 qkv (1536 tiles, 1-2 each)
// | grid.sync | phase3 flash on blocks 0..511 (2 active/CU = standalone config).
__global__ __launch_bounds__(256, 4) void fused_all(
    const float* __restrict__ hs, const int* __restrict__ mask,
    const float* __restrict__ Wq, const float* __restrict__ bq,
    const float* __restrict__ Wk, const float* __restrict__ bk,
    const float* __restrict__ Wv, const float* __restrict__ bv,
    float* __restrict__ out,
    unsigned short* __restrict__ Xb, unsigned short* __restrict__ Wb,
    unsigned short* __restrict__ Qb, unsigned short* __restrict__ Kb,
    unsigned short* __restrict__ Vt)
{
    __shared__ alignas(16) unsigned char smem[34816];

    cvt_body(hs, Wq, Wk, Wv, Xb, Wb);

    __threadfence();
    cg::this_grid().sync();

    for (int t = blockIdx.x; t < 1536; t += 1024)
        qkv_tile(t, smem, Xb, Wb, bq, bk, bv, Qb, Kb, Vt);

    __threadfence();
    cg::this_grid().sync();

    if (blockIdx.x < 512)
        flash_body(smem, blockIdx.x, Qb, Kb, Vt, mask, out);
}

// ================= fallback wrappers (R8 three-launch path) ========================
__global__ __launch_bounds__(256) void cvt_all_k(const float* __restrict__ hs,
    const float* __restrict__ w0, const float* __restrict__ w1,
    const float* __restrict__ w2, unsigned short* __restrict__ Xb,
    unsigned short* __restrict__ Wb) {
    cvt_body(hs, w0, w1, w2, Xb, Wb);
}

__global__ __launch_bounds__(256) void qkv_gemm_k(
    const unsigned short* __restrict__ Xb, const unsigned short* __restrict__ Wb,
    const float* __restrict__ bq, const float* __restrict__ bk, const float* __restrict__ bv,
    unsigned short* __restrict__ Qo, unsigned short* __restrict__ Ko,
    unsigned short* __restrict__ Vt) {
    __shared__ alignas(16) unsigned char smem[34816];
    int t = blockIdx.x + blockIdx.y * 64 + blockIdx.z * 512;
    qkv_tile(t, smem, Xb, Wb, bq, bk, bv, Qo, Ko, Vt);
}

__global__ __launch_bounds__(256, 2) void flash_attn_k(
    const unsigned short* __restrict__ Q, const unsigned short* __restrict__ K,
    const unsigned short* __restrict__ Vt, const int* __restrict__ mask,
    float* __restrict__ out) {
    __shared__ alignas(16) unsigned char smem[33024];
    flash_body(smem, blockIdx.y * gridDim.x + blockIdx.x, Q, K, Vt, mask, out);
}

extern "C" void kernel_launch(void* const* d_in, const int* in_sizes, int n_in,
                              void* d_out, int out_size, void* d_ws, size_t ws_size,
                              hipStream_t stream) {
    const float* hs  = (const float*)d_in[0];
    const int*  mask = (const int*)d_in[1];
    const float* Wq  = (const float*)d_in[2];
    const float* bq  = (const float*)d_in[3];
    const float* Wk  = (const float*)d_in[4];
    const float* bk  = (const float*)d_in[5];
    const float* Wv  = (const float*)d_in[6];
    const float* bv  = (const float*)d_in[7];
    float* out = (float*)d_out;

    char* ws = (char*)d_ws;
    unsigned short* Xb = (unsigned short*)(ws);                    // 16 MB
    unsigned short* Wb = (unsigned short*)(ws + 16777216);         // 6 MB
    unsigned short* Qb = (unsigned short*)(ws + 23068672);         // 16 MB
    unsigned short* Kb = (unsigned short*)(ws + 39845888);         // 16 MB
    unsigned short* Vt = (unsigned short*)(ws + 56623104);         // 16 MB

    // one-time capability probe: need 4 co-resident blocks/CU (1024 on 256 CUs)
    static int coop = -1;
    if (coop < 0) {
        int nb = 0;
        hipError_t e = hipOccupancyMaxActiveBlocksPerMultiprocessor(
            &nb, (const void*)fused_all, 256, 0);
        coop = (e == hipSuccess && nb >= 4) ? 1 : 0;
    }

    if (coop) {
        void* args[] = {(void*)&hs, (void*)&mask, (void*)&Wq, (void*)&bq,
                        (void*)&Wk, (void*)&bk, (void*)&Wv, (void*)&bv,
                        (void*)&out, (void*)&Xb, (void*)&Wb, (void*)&Qb,
                        (void*)&Kb, (void*)&Vt};
        hipError_t e = hipLaunchCooperativeKernel((const void*)fused_all,
                                                  dim3(1024), dim3(256),
                                                  args, 0, stream);
        if (e == hipSuccess) return;
        coop = 0;   // cooperative path unavailable -> fall through to 3-launch
    }

    cvt_all_k<<<dim3(11264), 256, 0, stream>>>(hs, Wq, Wk, Wv, Xb, Wb);
    qkv_gemm_k<<<dim3(64, 8, 3), 256, 0, stream>>>(Xb, Wb, bq, bk, bv, Qb, Kb, Vt);
    flash_attn_k<<<dim3(8, 64), 256, 0, stream>>>(Qb, Kb, Vt, mask, out);
}